// Round 6
// baseline (5537.053 us; speedup 1.0000x reference)
//
#include <hip/hip_runtime.h>

typedef float f32x4 __attribute__((ext_vector_type(4)));
typedef __bf16 bf16x8 __attribute__((ext_vector_type(8)));

#define HDIM 2048
#define BATCH 256
#define TSTEPS 300
#define NBLK 256
#define NTHR 256

// ws layout (bytes)
#define WT_OFF 0u            // 2048*2048 bf16 = 8388608 B, MFMA B-frag order
#define RBUF_OFF 8388608u    // 2 * 256*2048 bf16 = 2097152 B (double buffer)
#define WI_OFF 10485760u     // 4*2048 f32 = 32768 B
#define WO_OFF 10518528u     // 2*2048 f32 = 16384 B  ([o][j] layout)
#define BAR_OFF 10534912u    // 4 KB barrier area (same footprint as proven round 4)

// bar u32 indices (128B-spaced hot lines)
#define BX_CNT(x) ((x) * 32)         // per-XCD arrive counter (monotonic)
#define BX_GEN(x) (256 + (x) * 32)   // per-XCD generation
#define B_GCNT0 512                  // init barrier counter
#define B_XTOT(x) (544 + (x))        // per-XCD block totals

#define AGENT __HIP_MEMORY_SCOPE_AGENT

__device__ inline float tanh_fast(float x) {
  float e = __expf(2.0f * x);
  return 1.0f - 2.0f / (e + 1.0f);
}

__device__ inline unsigned short f2bf(float f) {
  union { float f; unsigned u; } v; v.f = f;
  unsigned r = v.u + 0x7fffu + ((v.u >> 16) & 1u);
  return (unsigned short)(r >> 16);
}

// Build wrec^T in bf16, MFMA B-frag order (verified rounds 1-4)
__global__ void prep_wt(const float* __restrict__ rec_noise,
                        const float* __restrict__ m, const float* __restrict__ n,
                        unsigned short* __restrict__ WT) {
  int base = (blockIdx.x * 256 + threadIdx.x) * 4;
#pragma unroll
  for (int ii = 0; ii < 4; ++ii) {
    int e = base + ii;
    int i = e & 7;
    int lane = (e >> 3) & 63;
    int t16 = (e >> 9) & 1;
    int kb = (e >> 10) & 63;
    int jg = e >> 16;
    int j = jg * 32 + t16 * 16 + (lane & 15);
    int k = kb * 32 + (lane >> 4) * 8 + i;
    float v = rec_noise[(size_t)j * HDIM + k] + m[j * 2] * n[k * 2] + m[j * 2 + 1] * n[k * 2 + 1];
    WT[e] = f2bf(v);
  }
}

__global__ void prep_small(const float* __restrict__ wi, const float* __restrict__ si,
                           const float* __restrict__ wo, const float* __restrict__ so,
                           const float* __restrict__ h0,
                           float* __restrict__ wi_full, float* __restrict__ wo_full,
                           unsigned short* __restrict__ r0) {
  int idx = blockIdx.x * 256 + threadIdx.x;
  if (idx < BATCH * HDIM) {
    int j = idx & (HDIM - 1);
    r0[idx] = f2bf(tanh_fast(h0[j]));
  }
  if (idx < 4 * HDIM) wi_full[idx] = wi[idx] * si[idx >> 11];
  if (idx < 2 * HDIM) {
    int o = idx >> 11, j = idx & (HDIM - 1);
    wo_full[idx] = wo[j * 2 + o] * so[o];
  }
}

// XCD-local persistent RNN: XCD x owns batch rows [32x, 32x+32); block i on that
// XCD owns output cols [64i, 64i+64). r/h never cross an XCD boundary, so the
// per-step sync needs NO wbl2 / NO sc1 invalidate: stores are in the local L2 at
// vmcnt-ack (hardware-proven by round 4, where a leader's wbl2 successfully
// flushed other blocks' stores), and readers only need a per-CU L1 buffer_inv.
// Flags are AGENT-scope atomics at MALL (proven codegen from rounds 2/4).
__global__ __launch_bounds__(NTHR, 1) void rnn_run(
    const float* __restrict__ inp, const float* __restrict__ noise,
    const unsigned short* __restrict__ WT, unsigned short* __restrict__ rbuf,
    const float* __restrict__ wi_full, const float* __restrict__ wo_full,
    const float* __restrict__ h0, float* __restrict__ out,
    unsigned* __restrict__ bar) {
  extern __shared__ unsigned short Wlds[];  // 128 KB

  const int tid = threadIdx.x;
  const int l = tid & 63, w = tid >> 6;
  const int lr = l & 15, hi = l >> 4;

  // ---- registration: discover (XCD, index-within-XCD, blocks-on-my-XCD) ----
  // (round-4-proven pattern; results staged through LDS, then LDS reused for W)
  if (tid == 0) {
    unsigned xcc_ = (unsigned)__builtin_amdgcn_s_getreg((31u << 11) | 20u) & 7u;  // HW_REG_XCC_ID
    unsigned idx_ = __hip_atomic_fetch_add(bar + B_XTOT(xcc_), 1u, __ATOMIC_RELAXED, AGENT);
    __hip_atomic_fetch_add(bar + B_GCNT0, 1u, __ATOMIC_RELEASE, AGENT);
    while (__hip_atomic_load(bar + B_GCNT0, __ATOMIC_RELAXED, AGENT) < (unsigned)NBLK)
      __builtin_amdgcn_s_sleep(1);
    __builtin_amdgcn_fence(__ATOMIC_ACQUIRE, "agent");
    unsigned nm_ = __hip_atomic_load(bar + B_XTOT(xcc_), __ATOMIC_RELAXED, AGENT);
    ((unsigned*)Wlds)[0] = xcc_;
    ((unsigned*)Wlds)[1] = idx_;
    ((unsigned*)Wlds)[2] = nm_;
  }
  __syncthreads();
  const int xcc = (int)((unsigned*)Wlds)[0];
  const int bi = (int)((unsigned*)Wlds)[1];        // [0,32) when distribution is uniform
  const unsigned n_mine = ((unsigned*)Wlds)[2];
  __syncthreads();

  const int rbase = xcc * 32;                  // my 32 batch rows
  const int jgw = 2 * bi + (w >> 1);           // this wave's 32-col group
  const int t16w = w & 1;
  const int colw = jgw * 32 + t16w * 16 + lr;  // this lane's output column

  unsigned* cnt = bar + BX_CNT(xcc);
  unsigned* gen = bar + BX_GEN(xcc);

  // ---- one-time: W K-half [0,1024) for my 64 cols -> LDS ----
#pragma unroll
  for (int jo = 0; jo < 2; ++jo) {
    const f32x4* src = (const f32x4*)(WT + (size_t)(2 * bi + jo) * 65536);
    f32x4* dst = (f32x4*)(Wlds + jo * 32768);
    for (int u = tid; u < 4096; u += NTHR) dst[u] = src[u];
  }

  float wic[4];
#pragma unroll
  for (int i = 0; i < 4; ++i) wic[i] = wi_full[i * HDIM + colw];
  const float wo0 = wo_full[colw], wo1 = wo_full[HDIM + colw];

  float h[2][4];
  {
    float a = h0[colw];
#pragma unroll
    for (int rt = 0; rt < 2; ++rt)
#pragma unroll
      for (int q = 0; q < 4; ++q) h[rt][q] = a;
  }
  __syncthreads();

  // prefetch t=0 noise + input-dot
  float nz[2][4], xd[2][4];
#pragma unroll
  for (int rt = 0; rt < 2; ++rt)
#pragma unroll
    for (int q = 0; q < 4; ++q) {
      const int brow = rbase + rt * 16 + hi * 4 + q;
      nz[rt][q] = noise[((size_t)brow * TSTEPS + 0) * HDIM + colw];
      float4 x = *(const float4*)(inp + ((size_t)brow * TSTEPS + 0) * 4);
      xd[rt][q] = x.x * wic[0] + x.y * wic[1] + x.z * wic[2] + x.w * wic[3];
    }

  const unsigned short* ldsB = Wlds + (w >> 1) * 32768 + t16w * 512 + l * 8;
  const unsigned short* glbB = WT + (size_t)jgw * 65536 + 32768 + t16w * 512 + l * 8;

  for (int t = 0; t < TSTEPS; ++t) {
    const unsigned short* rr = rbuf + (size_t)(t & 1) * (BATCH * HDIM);
    unsigned short* rw = rbuf + (size_t)((t + 1) & 1) * (BATCH * HDIM);

    // ---- rec = r_t @ wrec.T : rows [rbase,rbase+32) x cols [64bi,64bi+64) ----
    const unsigned short* A0 = rr + (size_t)(rbase + lr) * HDIM + hi * 8;
    const unsigned short* A1 = rr + (size_t)(rbase + 16 + lr) * HDIM + hi * 8;
    bf16x8 ar0[8], ar1[8];
#pragma unroll
    for (int i = 0; i < 8; ++i) {
      ar0[i] = *(const bf16x8*)(A0 + i * 32);
      ar1[i] = *(const bf16x8*)(A1 + i * 32);
    }
    f32x4 acc0e = {0.f, 0.f, 0.f, 0.f}, acc0o = {0.f, 0.f, 0.f, 0.f};
    f32x4 acc1e = {0.f, 0.f, 0.f, 0.f}, acc1o = {0.f, 0.f, 0.f, 0.f};
    bf16x8 bg[8];
#pragma unroll
    for (int kb = 0; kb < 32; ++kb) {  // K-half from LDS
      bf16x8 b = *(const bf16x8*)(ldsB + kb * 1024);
      if (kb & 1) {
        acc0o = __builtin_amdgcn_mfma_f32_16x16x32_bf16(ar0[kb & 7], b, acc0o, 0, 0, 0);
        acc1o = __builtin_amdgcn_mfma_f32_16x16x32_bf16(ar1[kb & 7], b, acc1o, 0, 0, 0);
      } else {
        acc0e = __builtin_amdgcn_mfma_f32_16x16x32_bf16(ar0[kb & 7], b, acc0e, 0, 0, 0);
        acc1e = __builtin_amdgcn_mfma_f32_16x16x32_bf16(ar1[kb & 7], b, acc1e, 0, 0, 0);
      }
      ar0[kb & 7] = *(const bf16x8*)(A0 + (kb + 8) * 32);
      ar1[kb & 7] = *(const bf16x8*)(A1 + (kb + 8) * 32);
      if (kb >= 24) bg[kb - 24] = *(const bf16x8*)(glbB + (kb - 24) * 1024);
    }
#pragma unroll
    for (int kb = 32; kb < 64; ++kb) {  // K-half streamed from own-XCD L2
      bf16x8 b = bg[kb & 7];
      if (kb & 1) {
        acc0o = __builtin_amdgcn_mfma_f32_16x16x32_bf16(ar0[kb & 7], b, acc0o, 0, 0, 0);
        acc1o = __builtin_amdgcn_mfma_f32_16x16x32_bf16(ar1[kb & 7], b, acc1o, 0, 0, 0);
      } else {
        acc0e = __builtin_amdgcn_mfma_f32_16x16x32_bf16(ar0[kb & 7], b, acc0e, 0, 0, 0);
        acc1e = __builtin_amdgcn_mfma_f32_16x16x32_bf16(ar1[kb & 7], b, acc1e, 0, 0, 0);
      }
      if (kb < 56) {
        ar0[kb & 7] = *(const bf16x8*)(A0 + (kb + 8) * 32);
        ar1[kb & 7] = *(const bf16x8*)(A1 + (kb + 8) * 32);
        bg[kb & 7] = *(const bf16x8*)(glbB + (kb - 24) * 1024);
      }
    }
    f32x4 acc0 = acc0e + acc0o, acc1 = acc1e + acc1o;

    // ---- h update + write r_{t+1} (plain stores -> own-XCD L2) ----
    float ro[2][4];
#pragma unroll
    for (int rt = 0; rt < 2; ++rt)
#pragma unroll
      for (int q = 0; q < 4; ++q) {
        float rec = (rt ? acc1[q] : acc0[q]);
        float hn = 0.8f * h[rt][q] + 0.05f * nz[rt][q] + 0.2f * (rec + xd[rt][q]);
        h[rt][q] = hn;
        float r_ = tanh_fast(hn);
        ro[rt][q] = r_;
        const int brow = rbase + rt * 16 + hi * 4 + q;
        rw[(size_t)brow * HDIM + colw] = f2bf(r_);
      }

    // ---- arrive: syncthreads drains vmcnt (stores ack'd in local L2 -- HW-proven
    //      by round 4's cross-CU wbl2 flush), then AGENT ticket at MALL ----
    __syncthreads();
    if (t + 1 < TSTEPS && tid == 0) {
      unsigned old = __hip_atomic_fetch_add(cnt, 1u, __ATOMIC_RELAXED, AGENT);
      if (old == n_mine * (unsigned)(t + 1) - 1u)
        __hip_atomic_store(gen, (unsigned)(t + 1), __ATOMIC_RELAXED, AGENT);
    }

    // ---- hidden under barrier: out_t from register r (f32, pre-round) ----
#pragma unroll
    for (int rt = 0; rt < 2; ++rt)
#pragma unroll
      for (int q = 0; q < 4; ++q) {
        float p0 = ro[rt][q] * wo0, p1 = ro[rt][q] * wo1;
        p0 += __shfl_xor(p0, 1, 64); p1 += __shfl_xor(p1, 1, 64);
        p0 += __shfl_xor(p0, 2, 64); p1 += __shfl_xor(p1, 2, 64);
        p0 += __shfl_xor(p0, 4, 64); p1 += __shfl_xor(p1, 4, 64);
        p0 += __shfl_xor(p0, 8, 64); p1 += __shfl_xor(p1, 8, 64);
        if (lr == 0) {
          const int brow = rbase + rt * 16 + hi * 4 + q;
          float* op = out + (size_t)brow * (TSTEPS * 2) + (size_t)t * 2;
          atomicAdd(op, p0);
          atomicAdd(op + 1, p1);
        }
      }

    if (t + 1 < TSTEPS) {
      // ---- hidden under barrier: prefetch t+1 noise + input-dot ----
#pragma unroll
      for (int rt = 0; rt < 2; ++rt)
#pragma unroll
        for (int q = 0; q < 4; ++q) {
          const int brow = rbase + rt * 16 + hi * 4 + q;
          nz[rt][q] = noise[((size_t)brow * TSTEPS + (t + 1)) * HDIM + colw];
          float4 x = *(const float4*)(inp + ((size_t)brow * TSTEPS + (t + 1)) * 4);
          xd[rt][q] = x.x * wic[0] + x.y * wic[1] + x.z * wic[2] + x.w * wic[3];
        }
      // ---- wait: relaxed AGENT poll (proven round 2/4 pattern) ----
      if (tid == 0) {
        while (__hip_atomic_load(gen, __ATOMIC_RELAXED, AGENT) < (unsigned)(t + 1))
          __builtin_amdgcn_s_sleep(1);
      }
      __syncthreads();
      // per-CU L1 invalidate so A-reads see same-XCD siblings' L2 data
      asm volatile("buffer_inv" ::: "memory");
      asm volatile("s_waitcnt vmcnt(0)" ::: "memory");
      __builtin_amdgcn_sched_barrier(0);
    }
  }
}

extern "C" void kernel_launch(void* const* d_in, const int* in_sizes, int n_in,
                              void* d_out, int out_size, void* d_ws, size_t ws_size,
                              hipStream_t stream) {
  const float* inp = (const float*)d_in[0];
  const float* noise = (const float*)d_in[1];
  const float* wi = (const float*)d_in[2];
  const float* si = (const float*)d_in[3];
  const float* m = (const float*)d_in[4];
  const float* n = (const float*)d_in[5];
  const float* rec_noise = (const float*)d_in[6];
  const float* wo = (const float*)d_in[7];
  const float* so = (const float*)d_in[8];
  const float* h0 = (const float*)d_in[9];

  char* ws = (char*)d_ws;
  unsigned short* WT = (unsigned short*)(ws + WT_OFF);
  unsigned short* rbuf = (unsigned short*)(ws + RBUF_OFF);
  float* wi_full = (float*)(ws + WI_OFF);
  float* wo_full = (float*)(ws + WO_OFF);
  unsigned* bar = (unsigned*)(ws + BAR_OFF);
  float* outp = (float*)d_out;

  // rebuild proxy params every call (ws is poisoned before timing)
  prep_wt<<<4096, 256, 0, stream>>>(rec_noise, m, n, WT);
  prep_small<<<2048, 256, 0, stream>>>(wi, si, wo, so, h0, wi_full, wo_full, rbuf);
  hipMemsetAsync(d_out, 0, (size_t)out_size * sizeof(float), stream);
  hipMemsetAsync(bar, 0, 4096, stream);

  hipFuncSetAttribute((const void*)rnn_run, hipFuncAttributeMaxDynamicSharedMemorySize, 131072);
  const unsigned short* WTc = WT;
  void* kargs[9] = {(void*)&inp, (void*)&noise, (void*)&WTc, (void*)&rbuf,
                    (void*)&wi_full, (void*)&wo_full, (void*)&h0, (void*)&outp,
                    (void*)&bar};
  hipError_t lerr = hipLaunchCooperativeKernel((void*)rnn_run, dim3(NBLK), dim3(NTHR),
                                               kargs, 131072, stream);
  if (lerr != hipSuccess) {
    // Fallback: plain launch. 256 blocks x 128KB LDS = 1 block/CU on 256 CUs ->
    // co-resident in practice; the in-kernel barrier handles the rest.
    rnn_run<<<dim3(NBLK), dim3(NTHR), 131072, stream>>>(
        inp, noise, WTc, rbuf, wi_full, wo_full, h0, outp, bar);
  }
}